// Round 6
// baseline (140.216 us; speedup 1.0000x reference)
//
#include <hip/hip_runtime.h>
#include <cstdint>
#include <cstddef>

typedef __bf16 bf16x8 __attribute__((ext_vector_type(8)));
typedef __bf16 bf16x4 __attribute__((ext_vector_type(4)));
typedef float f32x4 __attribute__((ext_vector_type(4)));
typedef unsigned short u16x4 __attribute__((ext_vector_type(4)));
typedef unsigned short u16x8 __attribute__((ext_vector_type(8)));

#define MFMA16(a, b, c) __builtin_amdgcn_mfma_f32_16x16x32_bf16(a, b, c, 0, 0, 0)

__device__ __forceinline__ unsigned short f2bf(float f) {
    unsigned u = __builtin_bit_cast(unsigned, f);
    u = (u + 0x7FFFu + ((u >> 16) & 1u)) >> 16;   // RNE
    return (unsigned short)u;
}

// ---------------------------------------------------------------- prep:
// blocks [0,1024)    : pe[n][d]  (f32, n-major)
// blocks [1024,1280) : peT[d][n] (f32, d-major) for the V-transposed epilogue
// blocks [1280,2048) : weights f32 -> bf16, fragment-chunked (linear):
//   Wb[tensor][d>>4][k>>5][d&15][k&31]  -> a wave's B-fragment = 1KB contiguous
__global__ __launch_bounds__(256)
void prep(float* __restrict__ pe, float* __restrict__ peT, unsigned short* __restrict__ Wb,
          const float* __restrict__ w0, const float* __restrict__ w1,
          const float* __restrict__ w2, const float* __restrict__ w3) {
    const int bx = blockIdx.x, t = threadIdx.x;
    const float LC = 0.03597789207808881f;  // ln(10000)/256
    if (bx < 1024) {
        int n = bx, d = t;
        float div = expf(-(float)(2 * (d >> 1)) * LC);
        float ang = (float)n * div;
        pe[n * 256 + d] = (d & 1) ? cosf(ang) : sinf(ang);
    } else if (bx < 1280) {
        int d = bx - 1024;
        float div = expf(-(float)(2 * (d >> 1)) * LC);
        f32x4 o;
        int n0 = t * 4;
#pragma unroll
        for (int e = 0; e < 4; ++e) {
            float ang = (float)(n0 + e) * div;
            o[e] = (d & 1) ? cosf(ang) : sinf(ang);
        }
        *(f32x4*)&peT[(size_t)d * 1024 + n0] = o;
    } else {
        int i = bx - 1280;                 // 0..767, 192 blocks per tensor
        int tensor = i / 192, blk = i - tensor * 192;
        const float* w = (tensor == 0) ? w0 : (tensor == 1) ? w1 : (tensor == 2) ? w2 : w3;
        int idx4 = blk * 256 + t;          // f32x4 index
        int d = idx4 / 192;                // 192 quads per 768-row
        int kq = (idx4 - d * 192) * 4;     // k base
        f32x4 v = *(const f32x4*)(w + (size_t)idx4 * 4);
        u16x4 o;
#pragma unroll
        for (int e = 0; e < 4; ++e) o[e] = f2bf(v[e]);
        unsigned short* dst = Wb + (size_t)tensor * 196608
                            + (d >> 4) * 12288 + (kq >> 5) * 512
                            + (d & 15) * 32 + (kq & 31);
        *(u16x4*)dst = o;
    }
}

// ---------------------------------------------------------------- patch embed v6
// Barrier-free, LDS-free. 256 thr = 4 independent waves; wave-tile = 32 patches
// x 256 d (exclusive patches -> A read exactly once, fully coalesced from the
// image). A: direct-to-VGPR, depth-3 rotating prefetch. W: bf16 chunked, 16 x
// 1KB wave-contiguous L2 loads/step in 2 batches of 8. BK=32, 24 K-steps.
struct EArgs {
    const float* src;
    const unsigned short* Wb;   // chunked bf16 weights (196608 elems)
    const float* bias;
    const float* pe;            // (1024,256) n-major
    const float* peT;           // (256,1024) d-major
    unsigned short* dst;
    int Np, lgNp, lgG, S, trans;
};

template<bool TR>
__device__ __forceinline__ void embed_body(const EArgs& A, int m0) {
    const int lane = threadIdx.x & 63;
    const int l15 = lane & 15, l4 = lane >> 4;
    const int S = A.S;
    const size_t S2 = (size_t)S * S;

    // per-lane A pointers: lane covers patch m0+i*16+l15, k-floats [8*l4, 8*l4+8)
    // of each 2-row K-step (row = l4>>1, col-offset = (l4&1)*8)
    const float* pbase[2];
    int nn[2], bb[2];
#pragma unroll
    for (int i = 0; i < 2; ++i) {
        int p = m0 + i * 16 + l15;
        int b = p >> A.lgNp, n = p & (A.Np - 1);
        nn[i] = n; bb[i] = b;
        int gy = n >> A.lgG, gx = n & ((1 << A.lgG) - 1);
        pbase[i] = A.src + ((size_t)(b * 3) * S + gy * 16 + (l4 >> 1)) * (size_t)S
                 + gx * 16 + (l4 & 1) * 8;
    }
    // per-lane W fragment base: frag j at + j*12288 + kt*512
    const unsigned short* wbase = A.Wb + l15 * 32 + l4 * 8;

    f32x4 acc[2][16];
#pragma unroll
    for (int i = 0; i < 2; ++i)
#pragma unroll
        for (int j = 0; j < 16; ++j) acc[i][j] = f32x4{0.f, 0.f, 0.f, 0.f};

    auto loadA = [&](int kt, f32x4* g) {
        size_t aoff = (size_t)(kt >> 3) * S2 + (size_t)((kt & 7) * 2) * (size_t)S;
        g[0] = *(const f32x4*)(pbase[0] + aoff);
        g[1] = *(const f32x4*)(pbase[0] + aoff + 4);
        g[2] = *(const f32x4*)(pbase[1] + aoff);
        g[3] = *(const f32x4*)(pbase[1] + aoff + 4);
    };

    // depth-3 rotating A prefetch (static slot under unroll-3)
    f32x4 apf[3][4];
    loadA(0, apf[0]);
    loadA(1, apf[1]);
    loadA(2, apf[2]);

#pragma unroll 3
    for (int kt = 0; kt < 24; ++kt) {
        const int sl = kt % 3;                  // static per unrolled instance
        bf16x8 pf[2];
#pragma unroll
        for (int i = 0; i < 2; ++i) {
            bf16x8 v;
#pragma unroll
            for (int e = 0; e < 4; ++e) {
                v[e]     = (__bf16)apf[sl][2 * i][e];
                v[4 + e] = (__bf16)apf[sl][2 * i + 1][e];
            }
            pf[i] = v;
        }
        if (kt < 21) loadA(kt + 3, apf[sl]);    // refill freed slot early

        // W batch 1 (d-tiles 0..7)
        bf16x8 wf[8];
#pragma unroll
        for (int j = 0; j < 8; ++j) {
            u16x8 r = *(const u16x8*)(wbase + (size_t)j * 12288 + kt * 512);
            wf[j] = __builtin_bit_cast(bf16x8, r);
        }
#pragma unroll
        for (int j = 0; j < 8; ++j)
#pragma unroll
            for (int i = 0; i < 2; ++i) {
                if (TR) acc[i][j] = MFMA16(pf[i], wf[j], acc[i][j]);
                else    acc[i][j] = MFMA16(wf[j], pf[i], acc[i][j]);
            }
        // W batch 2 (d-tiles 8..15)
#pragma unroll
        for (int j = 0; j < 8; ++j) {
            u16x8 r = *(const u16x8*)(wbase + (size_t)(8 + j) * 12288 + kt * 512);
            wf[j] = __builtin_bit_cast(bf16x8, r);
        }
#pragma unroll
        for (int j = 0; j < 8; ++j)
#pragma unroll
            for (int i = 0; i < 2; ++i) {
                if (TR) acc[i][8 + j] = MFMA16(pf[i], wf[j], acc[i][8 + j]);
                else    acc[i][8 + j] = MFMA16(wf[j], pf[i], acc[i][8 + j]);
            }
    }

    // ---- epilogue
    if (!TR) {
        // acc[i][j] = D[d][patch]: lane patch = l15, d-quad = j*16 + l4*4 + r
#pragma unroll
        for (int j = 0; j < 16; ++j) {
            int d0 = j * 16 + l4 * 4;
            int hh = d0 >> 5, hd = d0 & 31;
            f32x4 bs = *(const f32x4*)&A.bias[d0];
#pragma unroll
            for (int i = 0; i < 2; ++i) {
                int n = nn[i], b = bb[i];
                f32x4 pv = *(const f32x4*)&A.pe[n * 256 + d0];
                bf16x4 o;
#pragma unroll
                for (int r = 0; r < 4; ++r)
                    o[r] = (__bf16)(acc[i][j][r] + bs[r] + pv[r]);
                *(bf16x4*)&A.dst[(((size_t)(b * 8 + hh)) * A.Np + n) * 32 + hd] = o;
            }
        }
    } else {
        // acc[i][j] = D[patch][d]: lane d = j*16 + l15, patch-quad = i*16 + l4*4 + r
#pragma unroll
        for (int j = 0; j < 16; ++j) {
            int d = j * 16 + l15;
            int hh = d >> 5, hd = d & 31;
            float bsv = A.bias[d];
#pragma unroll
            for (int i = 0; i < 2; ++i) {
                int p0 = m0 + i * 16 + l4 * 4;
                int b = p0 >> A.lgNp, n0 = p0 & (A.Np - 1);
                f32x4 pv = *(const f32x4*)&A.peT[(size_t)d * 1024 + n0];
                bf16x4 o;
#pragma unroll
                for (int r = 0; r < 4; ++r)
                    o[r] = (__bf16)(acc[i][j][r] + bsv + pv[r]);
                *(bf16x4*)&A.dst[(((size_t)(b * 8 + hh)) * 32 + hd) * (size_t)A.Np + n0] = o;
            }
        }
    }
}

__global__ __launch_bounds__(256, 2)
void embed6(EArgs A0, EArgs A1, EArgs A2, EArgs A3) {
    const int bx = blockIdx.x;
    EArgs A; int lbx;
    if      (bx < 128) { A = A0; lbx = bx; }
    else if (bx < 256) { A = A1; lbx = bx - 128; }
    else if (bx < 384) { A = A2; lbx = bx - 256; }
    else               { A = A3; lbx = bx - 384; }
    const int m0 = lbx * 128 + (threadIdx.x >> 6) * 32;   // wave-exclusive 32 patches
    if (A.trans) embed_body<true>(A, m0);
    else         embed_body<false>(A, m0);
}

// ---------------------------------------------------------------- stage 2: Ks softmax + KV
__global__ __launch_bounds__(512)
void s2kv_kernel(const unsigned short* __restrict__ ah_ws,
                 const unsigned short* __restrict__ kh_ws,
                 const unsigned short* __restrict__ vT_ws,
                 unsigned short* __restrict__ kvT_ws) {
    __shared__ unsigned short ahs[128][40];
    __shared__ unsigned short khs[128][40];
    __shared__ unsigned short vts[32][136];
    __shared__ unsigned short Ps[128][136];

    const int bid = blockIdx.x;
    const int half = bid & 1;
    const int h = (bid >> 1) & 7, b = bid >> 4;
    const int a0 = half * 128;
    const int t = threadIdx.x, lane = t & 63, wid = t >> 6;
    const int l15 = lane & 15, l4 = lane >> 4;
    const size_t bh = (size_t)(b * 8 + h);

    const unsigned short* ahp = ah_ws + (bh * 256 + a0) * 32;
    const unsigned short* khp = kh_ws + bh * 1024 * 32;
    const unsigned short* vtp = vT_ws + bh * 32 * 1024;

    {
        int row = t >> 2, kq = (t & 3) * 8;
        *(u16x8*)&ahs[row][kq] = *(const u16x8*)(ahp + row * 32 + kq);
    }
    __syncthreads();
    const bf16x8 af = *(const bf16x8*)&ahs[wid * 16 + l15][l4 * 8];

    const float scale = 0.17677669529663687f;
    float rs[4] = {0.f, 0.f, 0.f, 0.f};
    const f32x4 z = {0.f, 0.f, 0.f, 0.f};
    f32x4 kv[2];
    kv[0] = z; kv[1] = z;

    for (int kt = 0; kt < 8; ++kt) {
        const int n0 = kt * 128;
        __syncthreads();
        {
            int row = t >> 2, kq = (t & 3) * 8;
            *(u16x8*)&khs[row][kq] = *(const u16x8*)(khp + (size_t)(n0 + row) * 32 + kq);
        }
        {
            int row = t >> 4, cq = (t & 15) * 8;
            *(u16x8*)&vts[row][cq] = *(const u16x8*)(vtp + (size_t)row * 1024 + n0 + cq);
        }
        __syncthreads();
#pragma unroll
        for (int n16 = 0; n16 < 8; ++n16) {
            bf16x8 bfr = *(const bf16x8*)&khs[n16 * 16 + l15][l4 * 8];
            f32x4 s = MFMA16(af, bfr, z);
#pragma unroll
            for (int r = 0; r < 4; ++r) {
                float e = __expf(s[r] * scale);
                rs[r] += e;
                Ps[wid * 16 + l4 * 4 + r][n16 * 16 + l15] = f2bf(e);
            }
        }
        __syncthreads();
#pragma unroll
        for (int ks = 0; ks < 4; ++ks) {
            bf16x8 pa = *(const bf16x8*)&Ps[wid * 16 + l15][ks * 32 + l4 * 8];
#pragma unroll
            for (int n16 = 0; n16 < 2; ++n16) {
                bf16x8 vb = *(const bf16x8*)&vts[n16 * 16 + l15][ks * 32 + l4 * 8];
                kv[n16] = MFMA16(pa, vb, kv[n16]);
            }
        }
    }
#pragma unroll
    for (int r = 0; r < 4; ++r) {
        rs[r] += __shfl_xor(rs[r], 1, 64);
        rs[r] += __shfl_xor(rs[r], 2, 64);
        rs[r] += __shfl_xor(rs[r], 4, 64);
        rs[r] += __shfl_xor(rs[r], 8, 64);
    }
#pragma unroll
    for (int n16 = 0; n16 < 2; ++n16)
#pragma unroll
        for (int r = 0; r < 4; ++r) {
            int m = a0 + wid * 16 + l4 * 4 + r;
            int d = n16 * 16 + l15;
            kvT_ws[bh * 8192 + (size_t)d * 256 + m] = f2bf(kv[n16][r] / rs[r]);
        }
}

// ---------------------------------------------------------------- stage 3: Qs softmax + A + unshuffle
__global__ __launch_bounds__(256)
void qsa_kernel(const unsigned short* __restrict__ qh_ws,
                const unsigned short* __restrict__ ah_ws,
                const unsigned short* __restrict__ kvT_ws,
                float* __restrict__ out) {
    __shared__ unsigned short qhs[64][40];
    __shared__ unsigned short ahs[256][40];
    __shared__ unsigned short kvt[32][264];
    __shared__ unsigned short Ps[64][264];

    const int bid = blockIdx.x;
    const int qt = bid & 15, h = (bid >> 4) & 7, b = bid >> 7;
    const int m0 = qt * 64;
    const int t = threadIdx.x, lane = t & 63, wid = t >> 6;
    const int l15 = lane & 15, l4 = lane >> 4;
    const size_t bh = (size_t)(b * 8 + h);

    const unsigned short* qhp = qh_ws + (bh * 1024 + m0) * 32;
    const unsigned short* ahp = ah_ws + bh * 256 * 32;

    {
        int row = t >> 2, kq = (t & 3) * 8;
        *(u16x8*)&qhs[row][kq] = *(const u16x8*)(qhp + row * 32 + kq);
    }
    {
        *(u16x8*)&ahs[t][0]  = *(const u16x8*)(ahp + (size_t)t * 32);
        *(u16x8*)&ahs[t][8]  = *(const u16x8*)(ahp + (size_t)t * 32 + 8);
        *(u16x8*)&ahs[t][16] = *(const u16x8*)(ahp + (size_t)t * 32 + 16);
        *(u16x8*)&ahs[t][24] = *(const u16x8*)(ahp + (size_t)t * 32 + 24);
    }
#pragma unroll
    for (int i = 0; i < 4; ++i) {
        int chunk = t + i * 256;
        int row = chunk >> 5, cq = (chunk & 31) * 8;
        *(u16x8*)&kvt[row][cq] = *(const u16x8*)(kvT_ws + bh * 8192 + (size_t)row * 256 + cq);
    }
    __syncthreads();

    const bf16x8 qa = *(const bf16x8*)&qhs[wid * 16 + l15][l4 * 8];
    const float scale = 0.17677669529663687f;
    const f32x4 z = {0.f, 0.f, 0.f, 0.f};
    float rs[4] = {0.f, 0.f, 0.f, 0.f};
#pragma unroll
    for (int n16 = 0; n16 < 16; ++n16) {
        bf16x8 bfr = *(const bf16x8*)&ahs[n16 * 16 + l15][l4 * 8];
        f32x4 s = MFMA16(qa, bfr, z);
#pragma unroll
        for (int r = 0; r < 4; ++r) {
            float e = __expf(s[r] * scale);
            rs[r] += e;
            Ps[wid * 16 + l4 * 4 + r][n16 * 16 + l15] = f2bf(e);
        }
    }
#pragma unroll
    for (int r = 0; r < 4; ++r) {
        rs[r] += __shfl_xor(rs[r], 1, 64);
        rs[r] += __shfl_xor(rs[r], 2, 64);
        rs[r] += __shfl_xor(rs[r], 4, 64);
        rs[r] += __shfl_xor(rs[r], 8, 64);
    }
    __syncthreads();

    f32x4 o[2];
    o[0] = z; o[1] = z;
#pragma unroll
    for (int ks = 0; ks < 8; ++ks) {
        bf16x8 pa = *(const bf16x8*)&Ps[wid * 16 + l15][ks * 32 + l4 * 8];
#pragma unroll
        for (int n16 = 0; n16 < 2; ++n16) {
            bf16x8 kb = *(const bf16x8*)&kvt[n16 * 16 + l15][ks * 32 + l4 * 8];
            o[n16] = MFMA16(pa, kb, o[n16]);
        }
    }
#pragma unroll
    for (int n16 = 0; n16 < 2; ++n16) {
#pragma unroll
        for (int r = 0; r < 4; ++r) {
            int row = wid * 16 + l4 * 4 + r;
            int n = m0 + row;
            int gy = n >> 5, gx = n & 31;
            int hd = n16 * 16 + l15;
            int py = 2 * h + (hd >> 4), px = hd & 15;
            out[((size_t)b * 512 + gy * 16 + py) * 512 + gx * 16 + px] = o[n16][r] / rs[r];
        }
    }
}

// ---------------------------------------------------------------- launch
extern "C" void kernel_launch(void* const* d_in, const int* in_sizes, int n_in,
                              void* d_out, int out_size, void* d_ws, size_t ws_size,
                              hipStream_t stream) {
    (void)in_sizes; (void)n_in; (void)out_size; (void)ws_size;

    const float* q  = (const float*)d_in[0];
    const float* k  = (const float*)d_in[1];
    const float* v  = (const float*)d_in[2];
    const float* a  = (const float*)d_in[3];
    const float* wq = (const float*)d_in[4];
    const float* bq = (const float*)d_in[5];
    const float* wk = (const float*)d_in[6];
    const float* bk = (const float*)d_in[7];
    const float* wv = (const float*)d_in[8];
    const float* bv = (const float*)d_in[9];
    const float* wa = (const float*)d_in[10];
    const float* ba = (const float*)d_in[11];
    float* out = (float*)d_out;

    // ws layout. pe/peT dead after embed6; kvT aliases that region.
    char* ws = (char*)d_ws;
    float* pe           = (float*)(ws);                        // 1 MB @ 0
    float* peT          = (float*)(ws + 1048576);              // 1 MB @ 1M
    unsigned short* Wb  = (unsigned short*)(ws + 2097152);     // 1.5 MB @ 2M
    unsigned short* kvT = (unsigned short*)(ws);               // 2 MB (aliases pe+peT)
    unsigned short* qh  = (unsigned short*)(ws + 3670016);     // 8 MB
    unsigned short* kh  = (unsigned short*)(ws + 12058624);    // 8 MB
    unsigned short* ah  = (unsigned short*)(ws + 20447232);    // 2 MB
    unsigned short* vT  = (unsigned short*)(ws + 22544384);    // 8 MB
    // total 30,932,992 bytes

    prep<<<2048, 256, 0, stream>>>(pe, peT, Wb, wq, wk, wv, wa);

    EArgs Aq = { q, Wb,              bq, pe, peT, qh, 1024, 10, 5, 512, 0 };
    EArgs Ak = { k, Wb + 196608,     bk, pe, peT, kh, 1024, 10, 5, 512, 0 };
    EArgs Av = { v, Wb + 2 * 196608, bv, pe, peT, vT, 1024, 10, 5, 512, 1 };
    EArgs Aa = { a, Wb + 3 * 196608, ba, pe, peT, ah,  256,  8, 4, 256, 0 };
    embed6<<<416, 256, 0, stream>>>(Aq, Ak, Av, Aa);

    s2kv_kernel<<<256, 512, 0, stream>>>(ah, kh, vT, kvT);
    qsa_kernel<<<2048, 256, 0, stream>>>(qh, ah, kvT, out);
}

// Round 7
// 132.367 us; speedup vs baseline: 1.0593x; 1.0593x over previous
//
#include <hip/hip_runtime.h>
#include <cstdint>
#include <cstddef>

typedef __bf16 bf16x8 __attribute__((ext_vector_type(8)));
typedef __bf16 bf16x4 __attribute__((ext_vector_type(4)));
typedef float f32x4 __attribute__((ext_vector_type(4)));
typedef unsigned short u16x4 __attribute__((ext_vector_type(4)));
typedef unsigned short u16x8 __attribute__((ext_vector_type(8)));

#define MFMA16(a, b, c) __builtin_amdgcn_mfma_f32_16x16x32_bf16(a, b, c, 0, 0, 0)

__device__ __forceinline__ unsigned short f2bf(float f) {
    unsigned u = __builtin_bit_cast(unsigned, f);
    u = (u + 0x7FFFu + ((u >> 16) & 1u)) >> 16;   // RNE
    return (unsigned short)u;
}

// ---------------------------------------------------------------- prep:
// blocks [0,1024)    : pe[n][d]  (f32, n-major)
// blocks [1024,1280) : peT[d][n] (f32, d-major) for the V-transposed epilogue
// blocks [1280,2048) : weights f32 -> bf16, fragment-chunked (linear):
//   Wb[tensor][d>>4][k>>5][d&15][k&31]  -> a wave's B-fragment = 1KB contiguous
__global__ __launch_bounds__(256)
void prep(float* __restrict__ pe, float* __restrict__ peT, unsigned short* __restrict__ Wb,
          const float* __restrict__ w0, const float* __restrict__ w1,
          const float* __restrict__ w2, const float* __restrict__ w3) {
    const int bx = blockIdx.x, t = threadIdx.x;
    const float LC = 0.03597789207808881f;  // ln(10000)/256
    if (bx < 1024) {
        int n = bx, d = t;
        float div = expf(-(float)(2 * (d >> 1)) * LC);
        float ang = (float)n * div;
        pe[n * 256 + d] = (d & 1) ? cosf(ang) : sinf(ang);
    } else if (bx < 1280) {
        int d = bx - 1024;
        float div = expf(-(float)(2 * (d >> 1)) * LC);
        f32x4 o;
        int n0 = t * 4;
#pragma unroll
        for (int e = 0; e < 4; ++e) {
            float ang = (float)(n0 + e) * div;
            o[e] = (d & 1) ? cosf(ang) : sinf(ang);
        }
        *(f32x4*)&peT[(size_t)d * 1024 + n0] = o;
    } else {
        int i = bx - 1280;                 // 0..767, 192 blocks per tensor
        int tensor = i / 192, blk = i - tensor * 192;
        const float* w = (tensor == 0) ? w0 : (tensor == 1) ? w1 : (tensor == 2) ? w2 : w3;
        int idx4 = blk * 256 + t;          // f32x4 index
        int d = idx4 / 192;                // 192 quads per 768-row
        int kq = (idx4 - d * 192) * 4;     // k base
        f32x4 v = *(const f32x4*)(w + (size_t)idx4 * 4);
        u16x4 o;
#pragma unroll
        for (int e = 0; e < 4; ++e) o[e] = f2bf(v[e]);
        unsigned short* dst = Wb + (size_t)tensor * 196608
                            + (d >> 4) * 12288 + (kq >> 5) * 512
                            + (d & 15) * 32 + (kq & 31);
        *(u16x4*)dst = o;
    }
}

// ---------------------------------------------------------------- patch embed v7
// Barrier-free, LDS-free register GEMM with high wave count.
// Block = 4 waves (2 patch-halves x 2 d-quarters) = 64 patches x 128 d.
// Wave-tile = 32 patches x 64 d, K=768, BK=32 (24 steps).
// A: f32 direct from image (read exactly once, coalesced), depth-2 rotation.
// W: chunked bf16 (1KB contiguous per frag), depth-2 rotation. No syncs at all.
struct EArgs {
    const float* src;
    const unsigned short* Wb;   // chunked bf16 weights (196608 elems)
    const float* bias;
    const float* pe;            // (1024,256) n-major
    const float* peT;           // (256,1024) d-major
    unsigned short* dst;
    int Np, lgNp, lgG, S, trans;
};

template<bool TR>
__device__ __forceinline__ void embed_body(const EArgs& A, int m0, int nh) {
    const int lane = threadIdx.x & 63, wid = threadIdx.x >> 6;
    const int l15 = lane & 15, l4 = lane >> 4;
    const int wr = wid >> 1, wc = wid & 1;   // wr: patch half, wc: d quarter
    const int S = A.S;
    const size_t S2 = (size_t)S * S;

    // per-lane A pointers: frag i covers patches m0+wr*32+i*16 .. +15;
    // lane: patch = +l15, k-octet = 8*l4 -> pixel row (l4>>1), col (l4&1)*8
    const float* pbase[2];
    int nn[2], bb[2];
#pragma unroll
    for (int i = 0; i < 2; ++i) {
        int p = m0 + wr * 32 + i * 16 + l15;
        int b = p >> A.lgNp, n = p & (A.Np - 1);
        nn[i] = n; bb[i] = b;
        int gy = n >> A.lgG, gx = n & ((1 << A.lgG) - 1);
        pbase[i] = A.src + ((size_t)(b * 3) * S + gy * 16 + (l4 >> 1)) * (size_t)S
                 + gx * 16 + (l4 & 1) * 8;
    }
    // per-lane W fragment base: d-tile jt = nh*8 + wc*4 + j
    const unsigned short* wbase = A.Wb + (size_t)(nh * 8 + wc * 4) * 12288
                                + l15 * 32 + l4 * 8;

    f32x4 acc[2][4];
#pragma unroll
    for (int i = 0; i < 2; ++i)
#pragma unroll
        for (int j = 0; j < 4; ++j) acc[i][j] = f32x4{0.f, 0.f, 0.f, 0.f};

    auto loadA = [&](int kt, f32x4* g) {
        size_t aoff = (size_t)(kt >> 3) * S2 + (size_t)((kt & 7) * 2) * (size_t)S;
        g[0] = *(const f32x4*)(pbase[0] + aoff);
        g[1] = *(const f32x4*)(pbase[0] + aoff + 4);
        g[2] = *(const f32x4*)(pbase[1] + aoff);
        g[3] = *(const f32x4*)(pbase[1] + aoff + 4);
    };
    auto loadW = [&](int kt, bf16x8* w) {
#pragma unroll
        for (int j = 0; j < 4; ++j) {
            u16x8 r = *(const u16x8*)(wbase + (size_t)j * 12288 + kt * 512);
            w[j] = __builtin_bit_cast(bf16x8, r);
        }
    };

    // depth-2 rotating prefetch on both operands
    f32x4 apf[2][4];
    bf16x8 wpf[2][4];
    loadA(0, apf[0]); loadW(0, wpf[0]);
    loadA(1, apf[1]); loadW(1, wpf[1]);

#pragma unroll 2
    for (int kt = 0; kt < 24; ++kt) {
        const int sl = kt & 1;                  // static under unroll-2
        bf16x8 pf[2];
#pragma unroll
        for (int i = 0; i < 2; ++i) {
            bf16x8 v;
#pragma unroll
            for (int e = 0; e < 4; ++e) {
                v[e]     = (__bf16)apf[sl][2 * i][e];
                v[4 + e] = (__bf16)apf[sl][2 * i + 1][e];
            }
            pf[i] = v;
        }
#pragma unroll
        for (int i = 0; i < 2; ++i)
#pragma unroll
            for (int j = 0; j < 4; ++j) {
                if (TR) acc[i][j] = MFMA16(pf[i], wpf[sl][j], acc[i][j]);  // D[patch][d]
                else    acc[i][j] = MFMA16(wpf[sl][j], pf[i], acc[i][j]);  // D[d][patch]
            }
        if (kt < 22) {                          // refill freed slot
            loadA(kt + 2, apf[sl]);
            loadW(kt + 2, wpf[sl]);
        }
    }

    // ---- epilogue
    if (!TR) {
        // acc[i][j] = D[d][patch]: lane patch = l15, d-quad = l4*4 + r
#pragma unroll
        for (int j = 0; j < 4; ++j) {
            int d0 = (nh * 8 + wc * 4 + j) * 16 + l4 * 4;
            int hh = d0 >> 5, hd = d0 & 31;
            f32x4 bs = *(const f32x4*)&A.bias[d0];
#pragma unroll
            for (int i = 0; i < 2; ++i) {
                int n = nn[i], b = bb[i];
                f32x4 pv = *(const f32x4*)&A.pe[n * 256 + d0];
                bf16x4 o;
#pragma unroll
                for (int r = 0; r < 4; ++r)
                    o[r] = (__bf16)(acc[i][j][r] + bs[r] + pv[r]);
                *(bf16x4*)&A.dst[(((size_t)(b * 8 + hh)) * A.Np + n) * 32 + hd] = o;
            }
        }
    } else {
        // acc[i][j] = D[patch][d]: lane d = l15 in tile, patch-quad = i*16 + l4*4 + r
#pragma unroll
        for (int j = 0; j < 4; ++j) {
            int d = (nh * 8 + wc * 4 + j) * 16 + l15;
            int hh = d >> 5, hd = d & 31;
            float bsv = A.bias[d];
#pragma unroll
            for (int i = 0; i < 2; ++i) {
                int p0 = m0 + wr * 32 + i * 16 + l4 * 4;
                int b = p0 >> A.lgNp, n0 = p0 & (A.Np - 1);
                f32x4 pv = *(const f32x4*)&A.peT[(size_t)d * 1024 + n0];
                bf16x4 o;
#pragma unroll
                for (int r = 0; r < 4; ++r)
                    o[r] = (__bf16)(acc[i][j][r] + bsv + pv[r]);
                *(bf16x4*)&A.dst[(((size_t)(b * 8 + hh)) * 32 + hd) * (size_t)A.Np + n0] = o;
            }
        }
    }
}

__global__ __launch_bounds__(256, 3)
void embed7(EArgs A0, EArgs A1, EArgs A2, EArgs A3) {
    const int bx = blockIdx.x;
    EArgs A; int lbx;
    if      (bx < 512)  { A = A0; lbx = bx; }
    else if (bx < 1024) { A = A1; lbx = bx - 512; }
    else if (bx < 1536) { A = A2; lbx = bx - 1024; }
    else                { A = A3; lbx = bx - 1536; }
    const int m0 = (lbx >> 1) * 64;
    const int nh = lbx & 1;
    if (A.trans) embed_body<true>(A, m0, nh);
    else         embed_body<false>(A, m0, nh);
}

// ---------------------------------------------------------------- stage 2: Ks softmax + KV
__global__ __launch_bounds__(512)
void s2kv_kernel(const unsigned short* __restrict__ ah_ws,
                 const unsigned short* __restrict__ kh_ws,
                 const unsigned short* __restrict__ vT_ws,
                 unsigned short* __restrict__ kvT_ws) {
    __shared__ unsigned short ahs[128][40];
    __shared__ unsigned short khs[128][40];
    __shared__ unsigned short vts[32][136];
    __shared__ unsigned short Ps[128][136];

    const int bid = blockIdx.x;
    const int half = bid & 1;
    const int h = (bid >> 1) & 7, b = bid >> 4;
    const int a0 = half * 128;
    const int t = threadIdx.x, lane = t & 63, wid = t >> 6;
    const int l15 = lane & 15, l4 = lane >> 4;
    const size_t bh = (size_t)(b * 8 + h);

    const unsigned short* ahp = ah_ws + (bh * 256 + a0) * 32;
    const unsigned short* khp = kh_ws + bh * 1024 * 32;
    const unsigned short* vtp = vT_ws + bh * 32 * 1024;

    {
        int row = t >> 2, kq = (t & 3) * 8;
        *(u16x8*)&ahs[row][kq] = *(const u16x8*)(ahp + row * 32 + kq);
    }
    __syncthreads();
    const bf16x8 af = *(const bf16x8*)&ahs[wid * 16 + l15][l4 * 8];

    const float scale = 0.17677669529663687f;
    float rs[4] = {0.f, 0.f, 0.f, 0.f};
    const f32x4 z = {0.f, 0.f, 0.f, 0.f};
    f32x4 kv[2];
    kv[0] = z; kv[1] = z;

    for (int kt = 0; kt < 8; ++kt) {
        const int n0 = kt * 128;
        __syncthreads();
        {
            int row = t >> 2, kq = (t & 3) * 8;
            *(u16x8*)&khs[row][kq] = *(const u16x8*)(khp + (size_t)(n0 + row) * 32 + kq);
        }
        {
            int row = t >> 4, cq = (t & 15) * 8;
            *(u16x8*)&vts[row][cq] = *(const u16x8*)(vtp + (size_t)row * 1024 + n0 + cq);
        }
        __syncthreads();
#pragma unroll
        for (int n16 = 0; n16 < 8; ++n16) {
            bf16x8 bfr = *(const bf16x8*)&khs[n16 * 16 + l15][l4 * 8];
            f32x4 s = MFMA16(af, bfr, z);
#pragma unroll
            for (int r = 0; r < 4; ++r) {
                float e = __expf(s[r] * scale);
                rs[r] += e;
                Ps[wid * 16 + l4 * 4 + r][n16 * 16 + l15] = f2bf(e);
            }
        }
        __syncthreads();
#pragma unroll
        for (int ks = 0; ks < 4; ++ks) {
            bf16x8 pa = *(const bf16x8*)&Ps[wid * 16 + l15][ks * 32 + l4 * 8];
#pragma unroll
            for (int n16 = 0; n16 < 2; ++n16) {
                bf16x8 vb = *(const bf16x8*)&vts[n16 * 16 + l15][ks * 32 + l4 * 8];
                kv[n16] = MFMA16(pa, vb, kv[n16]);
            }
        }
    }
#pragma unroll
    for (int r = 0; r < 4; ++r) {
        rs[r] += __shfl_xor(rs[r], 1, 64);
        rs[r] += __shfl_xor(rs[r], 2, 64);
        rs[r] += __shfl_xor(rs[r], 4, 64);
        rs[r] += __shfl_xor(rs[r], 8, 64);
    }
#pragma unroll
    for (int n16 = 0; n16 < 2; ++n16)
#pragma unroll
        for (int r = 0; r < 4; ++r) {
            int m = a0 + wid * 16 + l4 * 4 + r;
            int d = n16 * 16 + l15;
            kvT_ws[bh * 8192 + (size_t)d * 256 + m] = f2bf(kv[n16][r] / rs[r]);
        }
}

// ---------------------------------------------------------------- stage 3: Qs softmax + A + unshuffle
__global__ __launch_bounds__(256)
void qsa_kernel(const unsigned short* __restrict__ qh_ws,
                const unsigned short* __restrict__ ah_ws,
                const unsigned short* __restrict__ kvT_ws,
                float* __restrict__ out) {
    __shared__ unsigned short qhs[64][40];
    __shared__ unsigned short ahs[256][40];
    __shared__ unsigned short kvt[32][264];
    __shared__ unsigned short Ps[64][264];

    const int bid = blockIdx.x;
    const int qt = bid & 15, h = (bid >> 4) & 7, b = bid >> 7;
    const int m0 = qt * 64;
    const int t = threadIdx.x, lane = t & 63, wid = t >> 6;
    const int l15 = lane & 15, l4 = lane >> 4;
    const size_t bh = (size_t)(b * 8 + h);

    const unsigned short* qhp = qh_ws + (bh * 1024 + m0) * 32;
    const unsigned short* ahp = ah_ws + bh * 256 * 32;

    {
        int row = t >> 2, kq = (t & 3) * 8;
        *(u16x8*)&qhs[row][kq] = *(const u16x8*)(qhp + row * 32 + kq);
    }
    {
        *(u16x8*)&ahs[t][0]  = *(const u16x8*)(ahp + (size_t)t * 32);
        *(u16x8*)&ahs[t][8]  = *(const u16x8*)(ahp + (size_t)t * 32 + 8);
        *(u16x8*)&ahs[t][16] = *(const u16x8*)(ahp + (size_t)t * 32 + 16);
        *(u16x8*)&ahs[t][24] = *(const u16x8*)(ahp + (size_t)t * 32 + 24);
    }
#pragma unroll
    for (int i = 0; i < 4; ++i) {
        int chunk = t + i * 256;
        int row = chunk >> 5, cq = (chunk & 31) * 8;
        *(u16x8*)&kvt[row][cq] = *(const u16x8*)(kvT_ws + bh * 8192 + (size_t)row * 256 + cq);
    }
    __syncthreads();

    const bf16x8 qa = *(const bf16x8*)&qhs[wid * 16 + l15][l4 * 8];
    const float scale = 0.17677669529663687f;
    const f32x4 z = {0.f, 0.f, 0.f, 0.f};
    float rs[4] = {0.f, 0.f, 0.f, 0.f};
#pragma unroll
    for (int n16 = 0; n16 < 16; ++n16) {
        bf16x8 bfr = *(const bf16x8*)&ahs[n16 * 16 + l15][l4 * 8];
        f32x4 s = MFMA16(qa, bfr, z);
#pragma unroll
        for (int r = 0; r < 4; ++r) {
            float e = __expf(s[r] * scale);
            rs[r] += e;
            Ps[wid * 16 + l4 * 4 + r][n16 * 16 + l15] = f2bf(e);
        }
    }
#pragma unroll
    for (int r = 0; r < 4; ++r) {
        rs[r] += __shfl_xor(rs[r], 1, 64);
        rs[r] += __shfl_xor(rs[r], 2, 64);
        rs[r] += __shfl_xor(rs[r], 4, 64);
        rs[r] += __shfl_xor(rs[r], 8, 64);
    }
    __syncthreads();

    f32x4 o[2];
    o[0] = z; o[1] = z;
#pragma unroll
    for (int ks = 0; ks < 8; ++ks) {
        bf16x8 pa = *(const bf16x8*)&Ps[wid * 16 + l15][ks * 32 + l4 * 8];
#pragma unroll
        for (int n16 = 0; n16 < 2; ++n16) {
            bf16x8 kb = *(const bf16x8*)&kvt[n16 * 16 + l15][ks * 32 + l4 * 8];
            o[n16] = MFMA16(pa, kb, o[n16]);
        }
    }
#pragma unroll
    for (int n16 = 0; n16 < 2; ++n16) {
#pragma unroll
        for (int r = 0; r < 4; ++r) {
            int row = wid * 16 + l4 * 4 + r;
            int n = m0 + row;
            int gy = n >> 5, gx = n & 31;
            int hd = n16 * 16 + l15;
            int py = 2 * h + (hd >> 4), px = hd & 15;
            out[((size_t)b * 512 + gy * 16 + py) * 512 + gx * 16 + px] = o[n16][r] / rs[r];
        }
    }
}

// ---------------------------------------------------------------- launch
extern "C" void kernel_launch(void* const* d_in, const int* in_sizes, int n_in,
                              void* d_out, int out_size, void* d_ws, size_t ws_size,
                              hipStream_t stream) {
    (void)in_sizes; (void)n_in; (void)out_size; (void)ws_size;

    const float* q  = (const float*)d_in[0];
    const float* k  = (const float*)d_in[1];
    const float* v  = (const float*)d_in[2];
    const float* a  = (const float*)d_in[3];
    const float* wq = (const float*)d_in[4];
    const float* bq = (const float*)d_in[5];
    const float* wk = (const float*)d_in[6];
    const float* bk = (const float*)d_in[7];
    const float* wv = (const float*)d_in[8];
    const float* bv = (const float*)d_in[9];
    const float* wa = (const float*)d_in[10];
    const float* ba = (const float*)d_in[11];
    float* out = (float*)d_out;

    // ws layout. pe/peT dead after embed7; kvT aliases that region.
    char* ws = (char*)d_ws;
    float* pe           = (float*)(ws);                        // 1 MB @ 0
    float* peT          = (float*)(ws + 1048576);              // 1 MB @ 1M
    unsigned short* Wb  = (unsigned short*)(ws + 2097152);     // 1.5 MB @ 2M
    unsigned short* kvT = (unsigned short*)(ws);               // 2 MB (aliases pe+peT)
    unsigned short* qh  = (unsigned short*)(ws + 3670016);     // 8 MB
    unsigned short* kh  = (unsigned short*)(ws + 12058624);    // 8 MB
    unsigned short* ah  = (unsigned short*)(ws + 20447232);    // 2 MB
    unsigned short* vT  = (unsigned short*)(ws + 22544384);    // 8 MB
    // total 30,932,992 bytes

    prep<<<2048, 256, 0, stream>>>(pe, peT, Wb, wq, wk, wv, wa);

    EArgs Aq = { q, Wb,              bq, pe, peT, qh, 1024, 10, 5, 512, 0 };
    EArgs Ak = { k, Wb + 196608,     bk, pe, peT, kh, 1024, 10, 5, 512, 0 };
    EArgs Av = { v, Wb + 2 * 196608, bv, pe, peT, vT, 1024, 10, 5, 512, 1 };
    EArgs Aa = { a, Wb + 3 * 196608, ba, pe, peT, ah,  256,  8, 4, 256, 0 };
    embed7<<<1664, 256, 0, stream>>>(Aq, Ak, Av, Aa);

    s2kv_kernel<<<256, 512, 0, stream>>>(ah, kh, vT, kvT);
    qsa_kernel<<<2048, 256, 0, stream>>>(qh, ah, kvT, out);
}

// Round 8
// 108.898 us; speedup vs baseline: 1.2876x; 1.2155x over previous
//
#include <hip/hip_runtime.h>
#include <cstdint>
#include <cstddef>

typedef __bf16 bf16x8 __attribute__((ext_vector_type(8)));
typedef __bf16 bf16x4 __attribute__((ext_vector_type(4)));
typedef float f32x4 __attribute__((ext_vector_type(4)));
typedef unsigned short u16x4 __attribute__((ext_vector_type(4)));
typedef unsigned short u16x8 __attribute__((ext_vector_type(8)));

#define MFMA16(a, b, c) __builtin_amdgcn_mfma_f32_16x16x32_bf16(a, b, c, 0, 0, 0)

// async global->LDS, 16B per lane, LDS dest = wave-uniform base + lane*16
#define GLOAD16(g, l)                                                          \
    __builtin_amdgcn_global_load_lds(                                          \
        (const __attribute__((address_space(1))) unsigned int*)(g),            \
        (__attribute__((address_space(3))) unsigned int*)(l), 16, 0, 0)

__device__ __forceinline__ unsigned short f2bf(float f) {
    unsigned u = __builtin_bit_cast(unsigned, f);
    u = (u + 0x7FFFu + ((u >> 16) & 1u)) >> 16;   // RNE
    return (unsigned short)u;
}

// ---------------------------------------------------------------- prep:
// blocks [0,1024)    : pe[n][d]  (f32, n-major)
// blocks [1024,1280) : peT[d][n] (f32, d-major) for the V-transposed epilogue
// blocks [1280,2048) : weights f32 -> bf16, fragment-chunked (linear):
//   Wb[tensor][d>>4][k>>5][d&15][k&31]  -> a wave's B-fragment = 1KB contiguous
__global__ __launch_bounds__(256)
void prep(float* __restrict__ pe, float* __restrict__ peT, unsigned short* __restrict__ Wb,
          const float* __restrict__ w0, const float* __restrict__ w1,
          const float* __restrict__ w2, const float* __restrict__ w3) {
    const int bx = blockIdx.x, t = threadIdx.x;
    const float LC = 0.03597789207808881f;  // ln(10000)/256
    if (bx < 1024) {
        int n = bx, d = t;
        float div = expf(-(float)(2 * (d >> 1)) * LC);
        float ang = (float)n * div;
        pe[n * 256 + d] = (d & 1) ? cosf(ang) : sinf(ang);
    } else if (bx < 1280) {
        int d = bx - 1024;
        float div = expf(-(float)(2 * (d >> 1)) * LC);
        f32x4 o;
        int n0 = t * 4;
#pragma unroll
        for (int e = 0; e < 4; ++e) {
            float ang = (float)(n0 + e) * div;
            o[e] = (d & 1) ? cosf(ang) : sinf(ang);
        }
        *(f32x4*)&peT[(size_t)d * 1024 + n0] = o;
    } else {
        int i = bx - 1280;                 // 0..767, 192 blocks per tensor
        int tensor = i / 192, blk = i - tensor * 192;
        const float* w = (tensor == 0) ? w0 : (tensor == 1) ? w1 : (tensor == 2) ? w2 : w3;
        int idx4 = blk * 256 + t;          // f32x4 index
        int d = idx4 / 192;                // 192 quads per 768-row
        int kq = (idx4 - d * 192) * 4;     // k base
        f32x4 v = *(const f32x4*)(w + (size_t)idx4 * 4);
        u16x4 o;
#pragma unroll
        for (int e = 0; e < 4; ++e) o[e] = f2bf(v[e]);
        unsigned short* dst = Wb + (size_t)tensor * 196608
                            + (d >> 4) * 12288 + (kq >> 5) * 512
                            + (d & 15) * 32 + (kq & 31);
        *(u16x4*)dst = o;
    }
}

// ---------------------------------------------------------------- patch embed v8
// 64 patches x 128 d per block, 4 waves (2 patch-halves x 2 d-halves), BK=32,
// 24 K-steps. A: triple-buffered LDS via global_load_lds (XOR-swizzled),
// stage distance 2, ONE barrier per step. W: direct-to-reg depth-2 from
// L2-resident linear bf16 chunks. Counted vmcnt(6), never 0 in steady state.
struct EArgs {
    const float* src;
    const unsigned short* Wb;   // chunked bf16 weights (196608 elems)
    const float* bias;
    const float* pe;            // (1024,256) n-major
    const float* peT;           // (256,1024) d-major
    unsigned short* dst;
    int Np, lgNp, lgG, S, trans;
};

template<bool TR>
__device__ __forceinline__ void embed_body(const EArgs& A, int m0, int nh, float* Abuf) {
    const int t = threadIdx.x, lane = t & 63, wid = t >> 6;
    const int l15 = lane & 15, l4 = lane >> 4;
    const int wr = wid >> 1, wc = wid & 1;
    const int S = A.S;
    const size_t S2 = (size_t)S * S;

    // ---- per-lane A staging pointers: chunk cA = wid*2+i covers patches
    // cA*8..cA*8+7; lane>>3 = patch-in-chunk, phys slot = lane&7,
    // logical kq = (lane&7)^(lane>>3)  (both-sides XOR swizzle)
    const int kqL = (lane & 7) ^ (lane >> 3);
    const float* aP[2];
#pragma unroll
    for (int i = 0; i < 2; ++i) {
        int p = (wid * 2 + i) * 8 + (lane >> 3);
        int m = m0 + p;
        int b = m >> A.lgNp, n = m & (A.Np - 1);
        int gy = n >> A.lgG, gx = n & ((1 << A.lgG) - 1);
        aP[i] = A.src + ((size_t)(b * 3) * S + gy * 16 + (kqL >> 2)) * (size_t)S
              + gx * 16 + (kqL & 3) * 4;
    }
    // ---- per-lane W fragment base: d-tile jt = nh*8 + wc*4 + j
    const unsigned short* wbase = A.Wb + (size_t)(nh * 8 + wc * 4) * 12288
                                + l15 * 32 + l4 * 8;

    auto stageA = [&](int kt, int slot) {
        size_t aoff = (size_t)(kt >> 3) * S2 + (size_t)((kt & 7) * 2) * (size_t)S;
#pragma unroll
        for (int i = 0; i < 2; ++i)
            GLOAD16(aP[i] + aoff, Abuf + slot * 2048 + (wid * 2 + i) * 256);
    };
    auto loadW = [&](int kt, bf16x8* w) {
#pragma unroll
        for (int j = 0; j < 4; ++j) {
            u16x8 r = *(const u16x8*)(wbase + (size_t)j * 12288 + kt * 512);
            w[j] = __builtin_bit_cast(bf16x8, r);
        }
    };

    f32x4 acc[2][4];
#pragma unroll
    for (int i = 0; i < 2; ++i)
#pragma unroll
        for (int j = 0; j < 4; ++j) acc[i][j] = f32x4{0.f, 0.f, 0.f, 0.f};

    bf16x8 wpf[2][4];

    auto compute = [&](int slot, const bf16x8* wf) {
        // A frags: patch row p = wr*32 + i*16 + l15, logical kq {2l4, 2l4+1},
        // phys slot = kq ^ (p&7) = kq ^ (l15&7)
        bf16x8 pf[2];
#pragma unroll
        for (int i = 0; i < 2; ++i) {
            const char* base = (const char*)(Abuf + slot * 2048)
                             + (wr * 32 + i * 16 + l15) * 128;
            f32x4 lo = *(const f32x4*)(base + (((2 * l4) ^ (l15 & 7)) << 4));
            f32x4 hi = *(const f32x4*)(base + (((2 * l4 + 1) ^ (l15 & 7)) << 4));
            bf16x8 v;
#pragma unroll
            for (int e = 0; e < 4; ++e) { v[e] = (__bf16)lo[e]; v[4 + e] = (__bf16)hi[e]; }
            pf[i] = v;
        }
#pragma unroll
        for (int i = 0; i < 2; ++i)
#pragma unroll
            for (int j = 0; j < 4; ++j) {
                if (TR) acc[i][j] = MFMA16(pf[i], wf[j], acc[i][j]);  // D[patch][d]
                else    acc[i][j] = MFMA16(wf[j], pf[i], acc[i][j]);  // D[d][patch]
            }
    };

    // ---- prologue: A tiles 0,1 in flight; W tiles 0,1 in regs
    stageA(0, 0);
    stageA(1, 1);
    loadW(0, wpf[0]);
    loadW(1, wpf[1]);

    // ---- main loop: ONE barrier per step. Per iter issue: 2 A-gloads + 4 W.
    // vmcnt(6) = newest iter's 6 ops may be outstanding; A(kt),W(kt) forced.
#pragma unroll 6
    for (int kt = 0; kt < 22; ++kt) {
        asm volatile("s_waitcnt vmcnt(6)" ::: "memory");
        asm volatile("s_waitcnt lgkmcnt(0)" ::: "memory");  // prev step's ds_reads drained
        __builtin_amdgcn_sched_barrier(0);
        __builtin_amdgcn_s_barrier();
        compute(kt % 3, wpf[kt & 1]);
        stageA(kt + 2, (kt + 2) % 3);
        loadW(kt + 2, wpf[kt & 1]);
    }
    // kt = 22: outstanding = A(23),W(23)
    asm volatile("s_waitcnt vmcnt(6)" ::: "memory");
    asm volatile("s_waitcnt lgkmcnt(0)" ::: "memory");
    __builtin_amdgcn_sched_barrier(0);
    __builtin_amdgcn_s_barrier();
    compute(22 % 3, wpf[0]);
    // kt = 23
    asm volatile("s_waitcnt vmcnt(0)" ::: "memory");
    asm volatile("s_waitcnt lgkmcnt(0)" ::: "memory");
    __builtin_amdgcn_sched_barrier(0);
    __builtin_amdgcn_s_barrier();
    compute(23 % 3, wpf[1]);

    // ---- epilogue
    if (!TR) {
#pragma unroll
        for (int j = 0; j < 4; ++j) {
            int d0 = (nh * 8 + wc * 4 + j) * 16 + l4 * 4;
            int hh = d0 >> 5, hd = d0 & 31;
            f32x4 bs = *(const f32x4*)&A.bias[d0];
#pragma unroll
            for (int i = 0; i < 2; ++i) {
                int p = m0 + wr * 32 + i * 16 + l15;
                int b = p >> A.lgNp, n = p & (A.Np - 1);
                f32x4 pv = *(const f32x4*)&A.pe[n * 256 + d0];
                bf16x4 o;
#pragma unroll
                for (int r = 0; r < 4; ++r)
                    o[r] = (__bf16)(acc[i][j][r] + bs[r] + pv[r]);
                *(bf16x4*)&A.dst[(((size_t)(b * 8 + hh)) * A.Np + n) * 32 + hd] = o;
            }
        }
    } else {
#pragma unroll
        for (int j = 0; j < 4; ++j) {
            int d = (nh * 8 + wc * 4 + j) * 16 + l15;
            int hh = d >> 5, hd = d & 31;
            float bsv = A.bias[d];
#pragma unroll
            for (int i = 0; i < 2; ++i) {
                int p0 = m0 + wr * 32 + i * 16 + l4 * 4;
                int b = p0 >> A.lgNp, n0 = p0 & (A.Np - 1);
                f32x4 pv = *(const f32x4*)&A.peT[(size_t)d * 1024 + n0];
                bf16x4 o;
#pragma unroll
                for (int r = 0; r < 4; ++r)
                    o[r] = (__bf16)(acc[i][j][r] + bsv + pv[r]);
                *(bf16x4*)&A.dst[(((size_t)(b * 8 + hh)) * 32 + hd) * (size_t)A.Np + n0] = o;
            }
        }
    }
}

__global__ __launch_bounds__(256, 4)
void embed8(EArgs A0, EArgs A1, EArgs A2, EArgs A3) {
    __shared__ float Abuf[3][2048];            // 3 x 8 KB (64 patches x 32 k, f32)
    const int bx = blockIdx.x;
    EArgs A; int lbx;
    if      (bx < 512)  { A = A0; lbx = bx; }
    else if (bx < 1024) { A = A1; lbx = bx - 512; }
    else if (bx < 1536) { A = A2; lbx = bx - 1024; }
    else                { A = A3; lbx = bx - 1536; }
    const int m0 = (lbx >> 1) * 64;
    const int nh = lbx & 1;
    if (A.trans) embed_body<true>(A, m0, nh, &Abuf[0][0]);
    else         embed_body<false>(A, m0, nh, &Abuf[0][0]);
}

// ---------------------------------------------------------------- stage 2: Ks softmax + KV
__global__ __launch_bounds__(512)
void s2kv_kernel(const unsigned short* __restrict__ ah_ws,
                 const unsigned short* __restrict__ kh_ws,
                 const unsigned short* __restrict__ vT_ws,
                 unsigned short* __restrict__ kvT_ws) {
    __shared__ unsigned short ahs[128][40];
    __shared__ unsigned short khs[128][40];
    __shared__ unsigned short vts[32][136];
    __shared__ unsigned short Ps[128][136];

    const int bid = blockIdx.x;
    const int half = bid & 1;
    const int h = (bid >> 1) & 7, b = bid >> 4;
    const int a0 = half * 128;
    const int t = threadIdx.x, lane = t & 63, wid = t >> 6;
    const int l15 = lane & 15, l4 = lane >> 4;
    const size_t bh = (size_t)(b * 8 + h);

    const unsigned short* ahp = ah_ws + (bh * 256 + a0) * 32;
    const unsigned short* khp = kh_ws + bh * 1024 * 32;
    const unsigned short* vtp = vT_ws + bh * 32 * 1024;

    {
        int row = t >> 2, kq = (t & 3) * 8;
        *(u16x8*)&ahs[row][kq] = *(const u16x8*)(ahp + row * 32 + kq);
    }
    __syncthreads();
    const bf16x8 af = *(const bf16x8*)&ahs[wid * 16 + l15][l4 * 8];

    const float scale = 0.17677669529663687f;
    float rs[4] = {0.f, 0.f, 0.f, 0.f};
    const f32x4 z = {0.f, 0.f, 0.f, 0.f};
    f32x4 kv[2];
    kv[0] = z; kv[1] = z;

    for (int kt = 0; kt < 8; ++kt) {
        const int n0 = kt * 128;
        __syncthreads();
        {
            int row = t >> 2, kq = (t & 3) * 8;
            *(u16x8*)&khs[row][kq] = *(const u16x8*)(khp + (size_t)(n0 + row) * 32 + kq);
        }
        {
            int row = t >> 4, cq = (t & 15) * 8;
            *(u16x8*)&vts[row][cq] = *(const u16x8*)(vtp + (size_t)row * 1024 + n0 + cq);
        }
        __syncthreads();
#pragma unroll
        for (int n16 = 0; n16 < 8; ++n16) {
            bf16x8 bfr = *(const bf16x8*)&khs[n16 * 16 + l15][l4 * 8];
            f32x4 s = MFMA16(af, bfr, z);
#pragma unroll
            for (int r = 0; r < 4; ++r) {
                float e = __expf(s[r] * scale);
                rs[r] += e;
                Ps[wid * 16 + l4 * 4 + r][n16 * 16 + l15] = f2bf(e);
            }
        }
        __syncthreads();
#pragma unroll
        for (int ks = 0; ks < 4; ++ks) {
            bf16x8 pa = *(const bf16x8*)&Ps[wid * 16 + l15][ks * 32 + l4 * 8];
#pragma unroll
            for (int n16 = 0; n16 < 2; ++n16) {
                bf16x8 vb = *(const bf16x8*)&vts[n16 * 16 + l15][ks * 32 + l4 * 8];
                kv[n16] = MFMA16(pa, vb, kv[n16]);
            }
        }
    }
#pragma unroll
    for (int r = 0; r < 4; ++r) {
        rs[r] += __shfl_xor(rs[r], 1, 64);
        rs[r] += __shfl_xor(rs[r], 2, 64);
        rs[r] += __shfl_xor(rs[r], 4, 64);
        rs[r] += __shfl_xor(rs[r], 8, 64);
    }
#pragma unroll
    for (int n16 = 0; n16 < 2; ++n16)
#pragma unroll
        for (int r = 0; r < 4; ++r) {
            int m = a0 + wid * 16 + l4 * 4 + r;
            int d = n16 * 16 + l15;
            kvT_ws[bh * 8192 + (size_t)d * 256 + m] = f2bf(kv[n16][r] / rs[r]);
        }
}

// ---------------------------------------------------------------- stage 3: Qs softmax + A + unshuffle
__global__ __launch_bounds__(256)
void qsa_kernel(const unsigned short* __restrict__ qh_ws,
                const unsigned short* __restrict__ ah_ws,
                const unsigned short* __restrict__ kvT_ws,
                float* __restrict__ out) {
    __shared__ unsigned short qhs[64][40];
    __shared__ unsigned short ahs[256][40];
    __shared__ unsigned short kvt[32][264];
    __shared__ unsigned short Ps[64][264];

    const int bid = blockIdx.x;
    const int qt = bid & 15, h = (bid >> 4) & 7, b = bid >> 7;
    const int m0 = qt * 64;
    const int t = threadIdx.x, lane = t & 63, wid = t >> 6;
    const int l15 = lane & 15, l4 = lane >> 4;
    const size_t bh = (size_t)(b * 8 + h);

    const unsigned short* qhp = qh_ws + (bh * 1024 + m0) * 32;
    const unsigned short* ahp = ah_ws + bh * 256 * 32;

    {
        int row = t >> 2, kq = (t & 3) * 8;
        *(u16x8*)&qhs[row][kq] = *(const u16x8*)(qhp + row * 32 + kq);
    }
    {
        *(u16x8*)&ahs[t][0]  = *(const u16x8*)(ahp + (size_t)t * 32);
        *(u16x8*)&ahs[t][8]  = *(const u16x8*)(ahp + (size_t)t * 32 + 8);
        *(u16x8*)&ahs[t][16] = *(const u16x8*)(ahp + (size_t)t * 32 + 16);
        *(u16x8*)&ahs[t][24] = *(const u16x8*)(ahp + (size_t)t * 32 + 24);
    }
#pragma unroll
    for (int i = 0; i < 4; ++i) {
        int chunk = t + i * 256;
        int row = chunk >> 5, cq = (chunk & 31) * 8;
        *(u16x8*)&kvt[row][cq] = *(const u16x8*)(kvT_ws + bh * 8192 + (size_t)row * 256 + cq);
    }
    __syncthreads();

    const bf16x8 qa = *(const bf16x8*)&qhs[wid * 16 + l15][l4 * 8];
    const float scale = 0.17677669529663687f;
    const f32x4 z = {0.f, 0.f, 0.f, 0.f};
    float rs[4] = {0.f, 0.f, 0.f, 0.f};
#pragma unroll
    for (int n16 = 0; n16 < 16; ++n16) {
        bf16x8 bfr = *(const bf16x8*)&ahs[n16 * 16 + l15][l4 * 8];
        f32x4 s = MFMA16(qa, bfr, z);
#pragma unroll
        for (int r = 0; r < 4; ++r) {
            float e = __expf(s[r] * scale);
            rs[r] += e;
            Ps[wid * 16 + l4 * 4 + r][n16 * 16 + l15] = f2bf(e);
        }
    }
#pragma unroll
    for (int r = 0; r < 4; ++r) {
        rs[r] += __shfl_xor(rs[r], 1, 64);
        rs[r] += __shfl_xor(rs[r], 2, 64);
        rs[r] += __shfl_xor(rs[r], 4, 64);
        rs[r] += __shfl_xor(rs[r], 8, 64);
    }
    __syncthreads();

    f32x4 o[2];
    o[0] = z; o[1] = z;
#pragma unroll
    for (int ks = 0; ks < 8; ++ks) {
        bf16x8 pa = *(const bf16x8*)&Ps[wid * 16 + l15][ks * 32 + l4 * 8];
#pragma unroll
        for (int n16 = 0; n16 < 2; ++n16) {
            bf16x8 kb = *(const bf16x8*)&kvt[n16 * 16 + l15][ks * 32 + l4 * 8];
            o[n16] = MFMA16(pa, kb, o[n16]);
        }
    }
#pragma unroll
    for (int n16 = 0; n16 < 2; ++n16) {
#pragma unroll
        for (int r = 0; r < 4; ++r) {
            int row = wid * 16 + l4 * 4 + r;
            int n = m0 + row;
            int gy = n >> 5, gx = n & 31;
            int hd = n16 * 16 + l15;
            int py = 2 * h + (hd >> 4), px = hd & 15;
            out[((size_t)b * 512 + gy * 16 + py) * 512 + gx * 16 + px] = o[n16][r] / rs[r];
        }
    }
}

// ---------------------------------------------------------------- launch
extern "C" void kernel_launch(void* const* d_in, const int* in_sizes, int n_in,
                              void* d_out, int out_size, void* d_ws, size_t ws_size,
                              hipStream_t stream) {
    (void)in_sizes; (void)n_in; (void)out_size; (void)ws_size;

    const float* q  = (const float*)d_in[0];
    const float* k  = (const float*)d_in[1];
    const float* v  = (const float*)d_in[2];
    const float* a  = (const float*)d_in[3];
    const float* wq = (const float*)d_in[4];
    const float* bq = (const float*)d_in[5];
    const float* wk = (const float*)d_in[6];
    const float* bk = (const float*)d_in[7];
    const float* wv = (const float*)d_in[8];
    const float* bv = (const float*)d_in[9];
    const float* wa = (const float*)d_in[10];
    const float* ba = (const float*)d_in[11];
    float* out = (float*)d_out;

    // ws layout. pe/peT dead after embed8; kvT aliases that region.
    char* ws = (char*)d_ws;
    float* pe           = (float*)(ws);                        // 1 MB @ 0
    float* peT          = (float*)(ws + 1048576);              // 1 MB @ 1M
    unsigned short* Wb  = (unsigned short*)(ws + 2097152);     // 1.5 MB @ 2M
    unsigned short* kvT = (unsigned short*)(ws);               // 2 MB (aliases pe+peT)
    unsigned short* qh  = (unsigned short*)(ws + 3670016);     // 8 MB
    unsigned short* kh  = (unsigned short*)(ws + 12058624);    // 8 MB
    unsigned short* ah  = (unsigned short*)(ws + 20447232);    // 2 MB
    unsigned short* vT  = (unsigned short*)(ws + 22544384);    // 8 MB
    // total 30,932,992 bytes

    prep<<<2048, 256, 0, stream>>>(pe, peT, Wb, wq, wk, wv, wa);

    EArgs Aq = { q, Wb,              bq, pe, peT, qh, 1024, 10, 5, 512, 0 };
    EArgs Ak = { k, Wb + 196608,     bk, pe, peT, kh, 1024, 10, 5, 512, 0 };
    EArgs Av = { v, Wb + 2 * 196608, bv, pe, peT, vT, 1024, 10, 5, 512, 1 };
    EArgs Aa = { a, Wb + 3 * 196608, ba, pe, peT, ah,  256,  8, 4, 256, 0 };
    embed8<<<1664, 256, 0, stream>>>(Aq, Ak, Av, Aa);

    s2kv_kernel<<<256, 512, 0, stream>>>(ah, kh, vT, kvT);
    qsa_kernel<<<2048, 256, 0, stream>>>(qh, ah, kvT, out);
}